// Round 4
// baseline (465.844 us; speedup 1.0000x reference)
//
#include <hip/hip_runtime.h>

typedef unsigned short u16;
typedef unsigned int   u32;
typedef __bf16 bf16x8 __attribute__((ext_vector_type(8)));
typedef float  f32x4  __attribute__((ext_vector_type(4)));

#define S_LEN 4096
#define EMB   768

__device__ inline u16 f2b(float f) {
  union { float f; u32 u; } v; v.f = f;
  u32 r = v.u + 0x7FFFu + ((v.u >> 16) & 1u);
  return (u16)(r >> 16);
}

__device__ inline f32x4 mfma16(bf16x8 a, bf16x8 b, f32x4 c) {
  return __builtin_amdgcn_mfma_f32_16x16x32_bf16(a, b, c, 0, 0, 0);
}

__device__ inline void gload16(const void* g, void* l) {
  __builtin_amdgcn_global_load_lds(
      (const __attribute__((address_space(1))) u32*)g,
      (__attribute__((address_space(3))) u32*)l, 16, 0, 0);
}

// ---------------- cast x (fp32 -> bf16) ----------------
__global__ void cast_x_kernel(const float* __restrict__ x, u16* __restrict__ xb) {
  int i = (blockIdx.x * 256 + threadIdx.x) * 4;
  float4 v = *(const float4*)(x + i);
  ushort4 o; o.x = f2b(v.x); o.y = f2b(v.y); o.z = f2b(v.z); o.w = f2b(v.w);
  *(ushort4*)(xb + i) = o;
}

// ------------- cast + transpose weights: W[in][out] -> Wt[out][in] bf16 -------------
__global__ void castT_w_kernel(const float* __restrict__ w0, const float* __restrict__ w1,
                               const float* __restrict__ w2, const float* __restrict__ w3,
                               u16* __restrict__ wt) {
  __shared__ float t[32][33];
  int z = blockIdx.z;
  const float* W = (z == 0) ? w0 : ((z == 1) ? w1 : ((z == 2) ? w2 : w3));
  u16* Wt = wt + z * EMB * EMB;
  int tx = threadIdx.x & 31, ty = threadIdx.x >> 5;
  int bx = blockIdx.x * 32, by = blockIdx.y * 32;
#pragma unroll
  for (int i = 0; i < 4; i++) t[ty + 8 * i][tx] = W[(by + ty + 8 * i) * EMB + bx + tx];
  __syncthreads();
#pragma unroll
  for (int i = 0; i < 4; i++) Wt[(bx + ty + 8 * i) * EMB + by + tx] = f2b(t[tx][ty + 8 * i]);
}

// ------------- transpose v: v[s][768] -> Vt[768][s] (bf16) -------------
__global__ void transpose_v_kernel(const u16* __restrict__ v, u16* __restrict__ vt) {
  __shared__ u16 t[64][72];
  int bx = blockIdx.x * 64;  // column (hd) tile
  int by = blockIdx.y * 64;  // row (s) tile
  int c4 = threadIdx.x & 15, r = threadIdx.x >> 4;
#pragma unroll
  for (int i = 0; i < 4; i++) {
    ushort4 ld = *(const ushort4*)(v + (by + r + 16 * i) * EMB + bx + c4 * 4);
    t[r + 16 * i][c4 * 4 + 0] = ld.x; t[r + 16 * i][c4 * 4 + 1] = ld.y;
    t[r + 16 * i][c4 * 4 + 2] = ld.z; t[r + 16 * i][c4 * 4 + 3] = ld.w;
  }
  __syncthreads();
#pragma unroll
  for (int i = 0; i < 4; i++) {
    ushort4 st;
    st.x = t[c4 * 4 + 0][r + 16 * i]; st.y = t[c4 * 4 + 1][r + 16 * i];
    st.z = t[c4 * 4 + 2][r + 16 * i]; st.w = t[c4 * 4 + 3][r + 16 * i];
    *(ushort4*)(vt + (bx + r + 16 * i) * S_LEN + by + c4 * 4) = st;
  }
}

// ------------- GEMM: C[4096][768] = A[4096][768](bf16) @ Bt[768][768]^T + bias -------------
// Bt stored [N][K] (i.e. W^T), K contiguous. m97-style: 128x128 tile, BK=32,
// global_load_lds(16B), 2-phase double buffer, 4 waves each 64x64 (4x4 frags).
template <bool F32OUT>
__global__ __launch_bounds__(256, 2) void gemm_bt_kernel(
    const u16* __restrict__ A, const u16* __restrict__ Bt0,
    const float* __restrict__ b0, const float* __restrict__ b1, const float* __restrict__ b2,
    void* __restrict__ out0) {
  __shared__ u16 smem[2][8192];  // [buf][A:128*32 | B:128*32]
  int z = blockIdx.z;
  const u16* Bt = Bt0 + z * (EMB * EMB);
  const float* bias = (z == 0) ? b0 : ((z == 1) ? b1 : b2);
  int tid = threadIdx.x, wv = tid >> 6, lane = tid & 63, lg = lane >> 4, lq = lane & 15;
  int m0 = blockIdx.y * 128, n0 = blockIdx.x * 128;
  int wr = wv >> 1, wc = wv & 1;

  auto stage = [&](int buf, int kt) {
#pragma unroll
    for (int s = 0; s < 4; s++) {
      int i = wv * 4 + s;
      if (i < 8) {
        const u16* g = A + (m0 + i * 16 + (lane >> 2)) * EMB + kt * 32 + (lane & 3) * 8;
        gload16(g, &smem[buf][i * 512]);
      } else {
        int j = i - 8;
        const u16* g = Bt + (n0 + j * 16 + (lane >> 2)) * EMB + kt * 32 + (lane & 3) * 8;
        gload16(g, &smem[buf][4096 + j * 512]);
      }
    }
  };

  f32x4 acc[4][4];
#pragma unroll
  for (int a = 0; a < 4; a++)
#pragma unroll
    for (int b = 0; b < 4; b++) acc[a][b] = f32x4{0.f, 0.f, 0.f, 0.f};

  auto compute = [&](int buf) {
    const u16* As = &smem[buf][0] + wr * 2048;
    const u16* Bs = &smem[buf][4096] + wc * 2048;
    bf16x8 af[4], bfv[4];
#pragma unroll
    for (int mi = 0; mi < 4; mi++) af[mi] = *(const bf16x8*)(As + (mi * 16 + lq) * 32 + lg * 8);
#pragma unroll
    for (int ni = 0; ni < 4; ni++) bfv[ni] = *(const bf16x8*)(Bs + (ni * 16 + lq) * 32 + lg * 8);
#pragma unroll
    for (int mi = 0; mi < 4; mi++)
#pragma unroll
      for (int ni = 0; ni < 4; ni++) acc[mi][ni] = mfma16(af[mi], bfv[ni], acc[mi][ni]);
  };

  stage(0, 0);
  asm volatile("s_waitcnt vmcnt(0)" ::: "memory");
  __syncthreads();
  int cur = 0;
#pragma unroll 1
  for (int kt = 0; kt < 23; ++kt) {
    stage(cur ^ 1, kt + 1);
    compute(cur);
    asm volatile("s_waitcnt vmcnt(0)" ::: "memory");
    __syncthreads();
    cur ^= 1;
  }
  compute(cur);

  // epilogue: D[row=(lane>>4)*4+r][col=lane&15]
  int row_b = m0 + wr * 64 + lg * 4;
  int col_b = n0 + wc * 64 + lq;
#pragma unroll
  for (int ni = 0; ni < 4; ++ni) {
    int col = col_b + ni * 16;
    float bv = bias[col];
#pragma unroll
    for (int mi = 0; mi < 4; ++mi) {
      int row = row_b + mi * 16;
      f32x4 a = acc[mi][ni];
      if (F32OUT) {
        float* C = (float*)out0 + (size_t)z * (S_LEN * EMB);
#pragma unroll
        for (int r = 0; r < 4; r++) C[(row + r) * EMB + col] = a[r] + bv;
      } else {
        u16* C = (u16*)out0 + (size_t)z * (S_LEN * EMB);
#pragma unroll
        for (int r = 0; r < 4; r++) C[(row + r) * EMB + col] = f2b(a[r] + bv);
      }
    }
  }
}

// ------------- flash attention -------------
// grid (64 qblocks, 12 heads), 256 thr = 4 waves, wave w: 16 q-rows.
// Swapped QK^T: S^T = mfma(K_frag, Q^T_frag) -> D[key_loc][q=lane&15].
// P staged in wave-private LDS [16 q][64 keys + 8 pad]; PV: O^T = mfma(V^T, P^T),
// O-acc indexed by q=lane&15 (matches softmax state).
// Register-pressure schedule: load K(8 frags) -> QK^T (kf dies) -> issue V(8 frags)
// -> softmax (~200+ VALU cyc hides V latency; "memory" clobber on lgkmcnt pins
// vf loads above it) -> PV. Peak live ~110-130 VGPR, fits (256,3) cap (~168)
// so all 3 blocks/CU co-reside (12 waves/CU on the VMEM-latency-exposed loop).
__global__ __launch_bounds__(256, 3) void attn_kernel(
    const u16* __restrict__ qg, const u16* __restrict__ kg,
    const u16* __restrict__ vt, u16* __restrict__ og) {
  __shared__ u16 plds[4][16 * 72];
  int qb = blockIdx.x, h = blockIdx.y;
  int tid = threadIdx.x, w = tid >> 6, lane = tid & 63, lg = lane >> 4, lq = lane & 15;
  int q0 = qb * 64 + w * 16;
  u16* P = plds[w];
  const float CSC = 0.05205684446f;  // log2(e)/sqrt(768)

  bf16x8 qf0 = *(const bf16x8*)(qg + (q0 + lq) * EMB + h * 64 + lg * 8);
  bf16x8 qf1 = *(const bf16x8*)(qg + (q0 + lq) * EMB + h * 64 + lg * 8 + 32);

  f32x4 o0 = {0.f,0.f,0.f,0.f}, o1 = {0.f,0.f,0.f,0.f}, o2 = {0.f,0.f,0.f,0.f}, o3 = {0.f,0.f,0.f,0.f};
  float m_run = -3.0e38f, l_run = 0.f;
  const u16* kb = kg + h * 64 + lg * 8;
  const u16* vb = vt + (h * 64 + lq) * S_LEN + lg * 8;

#pragma unroll 1
  for (int kt = 0; kt < S_LEN / 64; ++kt) {
    int k0 = kt * 64;
    // ---- K fragments (8 loads in flight) ----
    bf16x8 kf[8];
#pragma unroll
    for (int t = 0; t < 4; t++) {
      const u16* kp = kb + (k0 + t * 16 + lq) * EMB;
      kf[2 * t]     = *(const bf16x8*)kp;
      kf[2 * t + 1] = *(const bf16x8*)(kp + 32);
    }
    // ---- QK^T (kf dies here) ----
    f32x4 sv[4];
#pragma unroll
    for (int t = 0; t < 4; t++) {
      f32x4 a = mfma16(kf[2 * t], qf0, f32x4{0.f, 0.f, 0.f, 0.f});
      sv[t] = mfma16(kf[2 * t + 1], qf1, a);
    }
    // ---- V fragments issued now; softmax below hides their latency ----
    bf16x8 vf[8];
    const u16* vp = vb + k0;
#pragma unroll
    for (int t = 0; t < 4; t++) {
      vf[2 * t]     = *(const bf16x8*)(vp + t * 16 * S_LEN);
      vf[2 * t + 1] = *(const bf16x8*)(vp + t * 16 * S_LEN + 32);
    }
    // ---- online softmax ----
    float sc[4][4]; float tm = -3.0e38f;
#pragma unroll
    for (int t = 0; t < 4; t++)
#pragma unroll
      for (int r = 0; r < 4; r++) { sc[t][r] = sv[t][r] * CSC; tm = fmaxf(tm, sc[t][r]); }
    tm = fmaxf(tm, __shfl_xor(tm, 16));
    tm = fmaxf(tm, __shfl_xor(tm, 32));
    float mn = fmaxf(m_run, tm);
    float alpha = exp2f(m_run - mn);
    m_run = mn;
    float ls = 0.f;
#pragma unroll
    for (int t = 0; t < 4; t++) {
      float p0 = exp2f(sc[t][0] - mn), p1 = exp2f(sc[t][1] - mn);
      float p2 = exp2f(sc[t][2] - mn), p3 = exp2f(sc[t][3] - mn);
      ls += (p0 + p1) + (p2 + p3);
      u32 w0 = (u32)f2b(p0) | ((u32)f2b(p1) << 16);
      u32 w1 = (u32)f2b(p2) | ((u32)f2b(p3) << 16);
      *(uint2*)(P + lq * 72 + t * 16 + lg * 4) = make_uint2(w0, w1);
    }
    l_run = l_run * alpha + ls;
    o0 *= alpha; o1 *= alpha; o2 *= alpha; o3 *= alpha;
    asm volatile("s_waitcnt lgkmcnt(0)" ::: "memory");
    bf16x8 pb0 = *(const bf16x8*)(P + lq * 72 + lg * 8);
    bf16x8 pb1 = *(const bf16x8*)(P + lq * 72 + 32 + lg * 8);
    // ---- PV ----
    o0 = mfma16(vf[0], pb0, o0);
    o0 = mfma16(vf[1], pb1, o0);
    o1 = mfma16(vf[2], pb0, o1);
    o1 = mfma16(vf[3], pb1, o1);
    o2 = mfma16(vf[4], pb0, o2);
    o2 = mfma16(vf[5], pb1, o2);
    o3 = mfma16(vf[6], pb0, o3);
    o3 = mfma16(vf[7], pb1, o3);
  }
  l_run += __shfl_xor(l_run, 16);
  l_run += __shfl_xor(l_run, 32);
  float inv = 1.0f / l_run;
  u16* ob = og + (q0 + lq) * EMB + h * 64 + lg * 4;
  {
    ushort4 s;
    s.x = f2b(o0[0] * inv); s.y = f2b(o0[1] * inv); s.z = f2b(o0[2] * inv); s.w = f2b(o0[3] * inv);
    *(ushort4*)(ob) = s;
    s.x = f2b(o1[0] * inv); s.y = f2b(o1[1] * inv); s.z = f2b(o1[2] * inv); s.w = f2b(o1[3] * inv);
    *(ushort4*)(ob + 16) = s;
    s.x = f2b(o2[0] * inv); s.y = f2b(o2[1] * inv); s.z = f2b(o2[2] * inv); s.w = f2b(o2[3] * inv);
    *(ushort4*)(ob + 32) = s;
    s.x = f2b(o3[0] * inv); s.y = f2b(o3[1] * inv); s.z = f2b(o3[2] * inv); s.w = f2b(o3[3] * inv);
    *(ushort4*)(ob + 48) = s;
  }
}

extern "C" void kernel_launch(void* const* d_in, const int* in_sizes, int n_in,
                              void* d_out, int out_size, void* d_ws, size_t ws_size,
                              hipStream_t stream) {
  const float* x  = (const float*)d_in[0];
  const float* Wq = (const float*)d_in[1];
  const float* bq = (const float*)d_in[2];
  const float* Wk = (const float*)d_in[3];
  const float* bk = (const float*)d_in[4];
  const float* Wv = (const float*)d_in[5];
  const float* bv = (const float*)d_in[6];
  const float* Wo = (const float*)d_in[7];
  const float* bo = (const float*)d_in[8];

  char* ws = (char*)d_ws;
  // Layout (36.2 MB total):
  //   [0,        6291456)  Xb: 4096*768 bf16  -- dead after QKV GEMM; reused as ao
  //   [6291456, 11010048)  Wt: 4*768*768 bf16 (Wq^T,Wk^T,Wv^T,Wo^T)
  //   [11010048,29884416)  qkv: 3*4096*768 bf16
  //   [29884416,36175872)  Vt: 768*4096 bf16
  u16* Xb  = (u16*)(ws);
  u16* Wt  = (u16*)(ws + 6291456);
  u16* qkv = (u16*)(ws + 11010048);
  u16* q   = qkv;
  u16* k   = qkv + 4096 * 768;
  u16* v   = qkv + 2 * 4096 * 768;
  u16* Vt  = (u16*)(ws + 29884416);
  u16* ao  = Xb;  // alias: Xb dead once QKV GEMM completes

  cast_x_kernel<<<3072, 256, 0, stream>>>(x, Xb);
  castT_w_kernel<<<dim3(24, 24, 4), 256, 0, stream>>>(Wq, Wk, Wv, Wo, Wt);
  gemm_bt_kernel<false><<<dim3(6, 32, 3), 256, 0, stream>>>(Xb, Wt, bq, bk, bv, qkv);
  transpose_v_kernel<<<dim3(12, 64), 256, 0, stream>>>(v, Vt);
  attn_kernel<<<dim3(64, 12), 256, 0, stream>>>(q, k, Vt, ao);
  gemm_bt_kernel<true><<<dim3(6, 32, 1), 256, 0, stream>>>(ao, Wt + 3 * EMB * EMB, bo, bo, bo, d_out);
}